// Round 6
// baseline (623.070 us; speedup 1.0000x reference)
//
#include <hip/hip_runtime.h>
#include <cmath>

#define NN 50000
#define NOCT 16
#define OCTW 3125            // 50000/16

typedef short v8s __attribute__((ext_vector_type(8)));   // 8 x bf16 (4 VGPRs)
typedef float v4f __attribute__((ext_vector_type(4)));

__device__ __forceinline__ float b2f(unsigned short u) {
    return __uint_as_float(((unsigned int)u) << 16);
}
__device__ __forceinline__ unsigned short f2b(float f) {
    unsigned int x = __float_as_uint(f);
    x += 0x7fffu + ((x >> 16) & 1u);          // round-to-nearest-even
    return (unsigned short)(x >> 16);
}

// async global->LDS, 16B per lane. LDS dest must be wave-contiguous (base + lane*16).
__device__ __forceinline__ void gld16(const void* g, void* l) {
    __builtin_amdgcn_global_load_lds(
        (const __attribute__((address_space(1))) unsigned int*)g,
        (__attribute__((address_space(3))) unsigned int*)l, 16, 0, 0);
}

// ---- dtype sniffer: mode=0 -> inputs are bf16, mode=1 -> inputs are float32 ----
__global__ void sniff_kernel(const unsigned short* __restrict__ x, int* __restrict__ mode) {
    if (threadIdx.x == 0 && blockIdx.x == 0) {
        int c = 0;
        for (int i = 0; i < 128; ++i) {
            unsigned int e = (x[i] >> 7) & 0xFFu;
            if (e >= 100u && e <= 140u) ++c;
        }
        *mode = (c >= 112) ? 0 : 1;
    }
}

// ---- keyed degree histogram: key = dst*16 + src/3125 ----
__global__ void deg_kernel(const int* __restrict__ src, const int* __restrict__ dst,
                           int* __restrict__ deg2, int E) {
    int e = blockIdx.x * blockDim.x + threadIdx.x;
    if (e < E) {
        unsigned int oct = (unsigned int)src[e] / OCTW;
        atomicAdd(&deg2[dst[e] * NOCT + oct], 1);
    }
}

// ---- hierarchical scan, stage 1: per-block (1024 elems) partial sums ----
__global__ void part_kernel(const int* __restrict__ deg, int* __restrict__ part, int n) {
    __shared__ int sm[256];
    int t = threadIdx.x;
    int base = blockIdx.x * 1024 + t * 4;
    int s = 0;
    if (base + 3 < n) {
        int4 v = *(const int4*)(deg + base);
        s = v.x + v.y + v.z + v.w;
    } else {
        for (int i = 0; i < 4; ++i) if (base + i < n) s += deg[base + i];
    }
    sm[t] = s;
    __syncthreads();
    for (int off = 128; off > 0; off >>= 1) {
        if (t < off) sm[t] += sm[t + off];
        __syncthreads();
    }
    if (t == 0) part[blockIdx.x] = sm[0];
}

// ---- stage 2: single block exclusive-scans up to 1024 partials (256 thr x 4) ----
__global__ void partscan_kernel(int* __restrict__ part, int nb) {
    __shared__ int sm[256];
    int t = threadIdx.x;
    int v[4]; int s = 0;
#pragma unroll
    for (int i = 0; i < 4; ++i) {
        int idx = t * 4 + i;
        v[i] = (idx < nb) ? part[idx] : 0;
        s += v[i];
    }
    sm[t] = s;
    __syncthreads();
    for (int off = 1; off < 256; off <<= 1) {
        int u = (t >= off) ? sm[t - off] : 0;
        __syncthreads();
        sm[t] += u;
        __syncthreads();
    }
    int run = sm[t] - s;
#pragma unroll
    for (int i = 0; i < 4; ++i) {
        int idx = t * 4 + i;
        if (idx < nb) { part[idx] = run; run += v[i]; }
    }
}

// ---- stage 3: block-local scan + offset; write row_ptr2 and cursor (cursor may
// alias deg2: each idx is read into regs by its owning thread before any write) ----
__global__ void scan2_kernel(const int* __restrict__ deg, const int* __restrict__ part,
                             int* __restrict__ row_ptr, int* __restrict__ cursor, int n) {
    __shared__ int sm[256];
    int t = threadIdx.x;
    int base = blockIdx.x * 1024 + t * 4;
    int d[4]; int s = 0;
#pragma unroll
    for (int i = 0; i < 4; ++i) { d[i] = (base + i < n) ? deg[base + i] : 0; s += d[i]; }
    sm[t] = s;
    __syncthreads();
    for (int off = 1; off < 256; off <<= 1) {
        int u = (t >= off) ? sm[t - off] : 0;
        __syncthreads();
        sm[t] += u;
        __syncthreads();
    }
    int run = part[blockIdx.x] + sm[t] - s;   // exclusive prefix at base
#pragma unroll
    for (int i = 0; i < 4; ++i) {
        int idx = base + i;
        if (idx < n) {
            row_ptr[idx] = run;
            cursor[idx]  = run;
            run += d[i];
            if (idx == n - 1) row_ptr[n] = run;   // total = E
        }
    }
}

// ---- dinv from octant row_ptr: deg(node) = rp2[16n+16] - rp2[16n] ----
__global__ void dinv_kernel(const int* __restrict__ rp2, float* __restrict__ dinv, int n) {
    int i = blockIdx.x * blockDim.x + threadIdx.x;
    if (i < n) {
        int d = rp2[i * NOCT + NOCT] - rp2[i * NOCT];
        dinv[i] = (d > 0) ? rsqrtf((float)d) : 0.0f;
    }
}

// ---- CSR fill (counting-sort placement, octant-keyed, ushort payload) ----
__global__ void fill_kernel(const int* __restrict__ src, const int* __restrict__ dst,
                            int* __restrict__ cursor, unsigned short* __restrict__ csr, int E) {
    int e = blockIdx.x * blockDim.x + threadIdx.x;
    if (e < E) {
        int sv = src[e];
        unsigned int oct = (unsigned int)sv / OCTW;
        int pos = atomicAdd(&cursor[dst[e] * NOCT + oct], 1);
        csr[pos] = (unsigned short)sv;
    }
}

// ---- W [K x F] (fp32 or bf16 per mode) -> WT [F x K] bf16 ----
__global__ void transpose_kernel(const void* __restrict__ W, unsigned short* __restrict__ WT,
                                 int K, int F, const int* __restrict__ modep) {
    int mode = *modep;
    int tid = blockIdx.x * blockDim.x + threadIdx.x;
    if (tid < K * F) {
        int n = tid / K, k = tid % K;
        unsigned short v = mode ? f2b(((const float*)W)[k * F + n])
                                : ((const unsigned short*)W)[k * F + n];
        WT[tid] = v;
    }
}

// ---- small convert (biases) ----
__global__ void cvt_kernel(const void* __restrict__ in, unsigned short* __restrict__ out,
                           int n, const int* __restrict__ modep) {
    int mode = *modep;
    int i = blockIdx.x * blockDim.x + threadIdx.x;
    if (i < n) out[i] = mode ? f2b(((const float*)in)[i]) : ((const unsigned short*)in)[i];
}

// ---- pack x (50000x128) into buf cols 0:128 (ld 512), 16B chunks ----
__global__ void pack_kernel(const void* __restrict__ x, unsigned short* __restrict__ buf,
                            const int* __restrict__ modep) {
    int mode = *modep;
    int tid = blockIdx.x * blockDim.x + threadIdx.x;
    if (tid < NN * 16) {                       // 16 chunks of 8 bf16 per row
        int n = tid >> 4, c = tid & 15;
        if (mode == 0) {
            ((uint4*)buf)[n * 64 + c] = ((const uint4*)x)[n * 16 + c];
        } else {
            const float* xf = (const float*)x + (size_t)n * 128 + c * 8;
            unsigned short o[8];
#pragma unroll
            for (int i = 0; i < 8; ++i) o[i] = f2b(xf[i]);
            *(uint4*)&buf[(size_t)n * 512 + c * 8] = *(const uint4*)o;
        }
    }
}

// ---- SpMM: one wave per dst node; edges octant-sorted by src for L2 locality ----
template <int FPL>   // features per lane: F = 64*FPL (2 -> 128, 4 -> 256)
__global__ void spmm_kernel(const unsigned short* __restrict__ h, int ldh,
                            const int* __restrict__ rp2, const unsigned short* __restrict__ csr,
                            const float* __restrict__ dinv,
                            unsigned short* __restrict__ out, int ldo) {
    int node = blockIdx.x * 4 + (threadIdx.x >> 6);
    int lane = threadIdx.x & 63;
    int beg = rp2[node * NOCT], end = rp2[node * NOCT + NOCT];
    float acc[FPL];
#pragma unroll
    for (int i = 0; i < FPL; ++i) acc[i] = 0.f;
    const int col = lane * FPL;

    for (int base = beg; base < end; base += 64) {
        int cnt = min(64, end - base);
        int idx = base + lane;
        int sl = (int)csr[(idx < end) ? idx : base];   // coalesced batch (src-sorted)
        float dl = dinv[sl];                            // one gather per 64 edges
        int g = 0;
        for (; g + 8 <= cnt; g += 8) {
            int s[8]; float d[8];
#pragma unroll
            for (int i = 0; i < 8; ++i) { s[i] = __shfl(sl, g + i); d[i] = __shfl(dl, g + i); }
            if (FPL == 4) {
                ushort4 v[8];
#pragma unroll
                for (int i = 0; i < 8; ++i)
                    v[i] = *(const ushort4*)(h + (size_t)s[i] * ldh + col);
#pragma unroll
                for (int i = 0; i < 8; ++i) {
                    acc[0] += d[i] * b2f(v[i].x); acc[1] += d[i] * b2f(v[i].y);
                    acc[2] += d[i] * b2f(v[i].z); acc[3] += d[i] * b2f(v[i].w);
                }
            } else {
                ushort2 v[8];
#pragma unroll
                for (int i = 0; i < 8; ++i)
                    v[i] = *(const ushort2*)(h + (size_t)s[i] * ldh + col);
#pragma unroll
                for (int i = 0; i < 8; ++i) {
                    acc[0] += d[i] * b2f(v[i].x); acc[1] += d[i] * b2f(v[i].y);
                }
            }
        }
        for (; g < cnt; ++g) {
            int sg = __shfl(sl, g);
            float dg = __shfl(dl, g);
            const unsigned short* hp = h + (size_t)sg * ldh + col;
            if (FPL == 4) {
                ushort4 v = *(const ushort4*)hp;
                acc[0] += dg * b2f(v.x); acc[1] += dg * b2f(v.y);
                acc[2] += dg * b2f(v.z); acc[3] += dg * b2f(v.w);
            } else {
                ushort2 v = *(const ushort2*)hp;
                acc[0] += dg * b2f(v.x); acc[1] += dg * b2f(v.y);
            }
        }
    }

    float dn = -dinv[node];
    unsigned short* op = out + (size_t)node * ldo + col;
    if (FPL == 4) {
        ushort4 o;
        o.x = f2b(acc[0] * dn); o.y = f2b(acc[1] * dn);
        o.z = f2b(acc[2] * dn); o.w = f2b(acc[3] * dn);
        *(ushort4*)op = o;
    } else {
        ushort2 o;
        o.x = f2b(acc[0] * dn); o.y = f2b(acc[1] * dn);
        *(ushort2*)op = o;
    }
}

// ---- LDS-staged MFMA GEMM, 128(M) x NQ*64(N) block tile, 2*NQ waves ----
// Wave w: rows (w/NQ)*64..+64, cols (w%NQ)*64..+64; 4x4 mfma tiles, acc 64 VGPR.
// Block covers full output width -> owns its rows -> in-place safe (all K-loop
// A reads complete before epilogue stores; clamped tail row belongs to last block).
template <int K32, int NQ>
__global__ void gemm_lds_kernel(const unsigned short* __restrict__ A, int lda,
                                const unsigned short* __restrict__ WT,   // [NQ*64 x K] bf16
                                const unsigned short* __restrict__ bias, // bf16
                                void* __restrict__ out, int ldo,
                                int M, int dotanh, int is_final, const int* __restrict__ modep) {
    constexpr int K    = K32 * 32;
    constexpr int NB   = NQ * 64;
    constexpr int NTHR = 2 * NQ * 64;
    constexpr int ACH  = 128 * 4;                     // 16B chunks of A tile
    constexpr int BCH  = NB * 4;
    constexpr int ROUNDS = (ACH + BCH) / NTHR;
    __shared__ unsigned short lds[(128 + NB) * 32];   // A[128][32] then B[NB][32]

    const int tid = threadIdx.x;
    const int wave = tid >> 6, lane = tid & 63, quad = lane >> 4, l16 = lane & 15;
    const int mh = wave / NQ, nq = wave % NQ;
    const int m0 = blockIdx.x * 128;

    v4f acc[4][4];
#pragma unroll
    for (int mi = 0; mi < 4; ++mi)
#pragma unroll
        for (int ni = 0; ni < 4; ++ni) acc[mi][ni] = (v4f){0.f, 0.f, 0.f, 0.f};

    const unsigned short* gp[ROUNDS];
#pragma unroll
    for (int r = 0; r < ROUNDS; ++r) {
        int c = tid + r * NTHR;
        if (c < ACH) {
            int row = m0 + (c >> 2);
            if (row >= M) row = M - 1;
            gp[r] = A + (size_t)row * lda + (c & 3) * 8;
        } else {
            int cb = c - ACH;
            gp[r] = WT + (size_t)(cb >> 2) * K + (cb & 3) * 8;
        }
    }

    const unsigned short* aT = lds;
    const unsigned short* bT = lds + 128 * 32;

    for (int k0 = 0; k0 < K; k0 += 32) {
#pragma unroll
        for (int r = 0; r < ROUNDS; ++r) {
            int c = tid + r * NTHR;
            gld16(gp[r] + k0, (void*)&lds[c * 8]);
        }
        __syncthreads();

        v8s a_frag[4], b_frag[4];
#pragma unroll
        for (int mi = 0; mi < 4; ++mi)
            a_frag[mi] = *(const v8s*)&aT[(mh * 64 + mi * 16 + l16) * 32 + quad * 8];
#pragma unroll
        for (int ni = 0; ni < 4; ++ni)
            b_frag[ni] = *(const v8s*)&bT[(nq * 64 + ni * 16 + l16) * 32 + quad * 8];
#pragma unroll
        for (int mi = 0; mi < 4; ++mi)
#pragma unroll
            for (int ni = 0; ni < 4; ++ni)
                acc[mi][ni] = __builtin_amdgcn_mfma_f32_16x16x32_bf16(a_frag[mi], b_frag[ni],
                                                                      acc[mi][ni], 0, 0, 0);
        __syncthreads();
    }

    int fin = is_final ? *modep : 0;
#pragma unroll
    for (int ni = 0; ni < 4; ++ni) {
        int colc = nq * 64 + ni * 16 + l16;
        float bv = b2f(bias[colc]);
#pragma unroll
        for (int mi = 0; mi < 4; ++mi) {
#pragma unroll
            for (int r = 0; r < 4; ++r) {
                int row = m0 + mh * 64 + mi * 16 + quad * 4 + r;
                if (row < M) {
                    float v = acc[mi][ni][r] + bv;
                    if (dotanh) v = tanhf(v);
                    if (fin) ((float*)out)[(size_t)row * ldo + colc] = v;
                    else     ((unsigned short*)out)[(size_t)row * ldo + colc] = f2b(v);
                }
            }
        }
    }
}

static inline size_t al256(size_t x) { return (x + 255) & ~(size_t)255; }

extern "C" void kernel_launch(void* const* d_in, const int* in_sizes, int n_in,
                              void* d_out, int out_size, void* d_ws, size_t ws_size,
                              hipStream_t stream) {
    const void* x  = d_in[0];
    const int* src = (const int*)d_in[1];
    const int* dst = (const int*)d_in[2];
    const void* W1 = d_in[3]; const void* b1 = d_in[4];
    const void* W2 = d_in[5]; const void* b2 = d_in[6];
    const void* W3 = d_in[7]; const void* b3 = d_in[8];
    const int E = in_sizes[1];
    const int NK = NN * NOCT;              // 800000 keys

    // workspace carve-up (~60.3 MB)
    char* p = (char*)d_ws;
    int* mode     = (int*)p;            p += 256;
    int* deg2     = (int*)p;            p += al256((size_t)NK * 4);        // aliased as cursor
    int* rp2      = (int*)p;            p += al256((size_t)(NK + 1) * 4);
    float* dinv   = (float*)p;          p += al256((size_t)NN * 4);
    int* part     = (int*)p;            p += al256((size_t)1024 * 4);
    unsigned short* csr = (unsigned short*)p; p += al256((size_t)E * 2);
    unsigned short* WT1 = (unsigned short*)p; p += al256((size_t)256 * 256 * 2);
    unsigned short* WT2 = (unsigned short*)p; p += al256((size_t)256 * 512 * 2);
    unsigned short* WT3 = (unsigned short*)p; p += al256((size_t)128 * 512 * 2);
    unsigned short* bb1 = (unsigned short*)p; p += al256((size_t)256 * 2);
    unsigned short* bb2 = (unsigned short*)p; p += al256((size_t)256 * 2);
    unsigned short* bb3 = (unsigned short*)p; p += al256((size_t)128 * 2);
    unsigned short* buf = (unsigned short*)p; p += al256((size_t)NN * 512 * 2);

    hipMemsetAsync(deg2, 0, (size_t)NK * 4, stream);
    sniff_kernel<<<1, 64, 0, stream>>>((const unsigned short*)x, mode);

    int eb = (E + 255) / 256;
    const int SB = (NK + 1023) / 1024;     // 782 scan blocks
    deg_kernel<<<eb, 256, 0, stream>>>(src, dst, deg2, E);
    part_kernel<<<SB, 256, 0, stream>>>(deg2, part, NK);
    partscan_kernel<<<1, 256, 0, stream>>>(part, SB);
    scan2_kernel<<<SB, 256, 0, stream>>>(deg2, part, rp2, deg2 /*cursor alias*/, NK);
    dinv_kernel<<<(NN + 255) / 256, 256, 0, stream>>>(rp2, dinv, NN);
    fill_kernel<<<eb, 256, 0, stream>>>(src, dst, deg2 /*cursor*/, csr, E);

    transpose_kernel<<<(256 * 256 + 255) / 256, 256, 0, stream>>>(W1, WT1, 256, 256, mode);
    transpose_kernel<<<(512 * 256 + 255) / 256, 256, 0, stream>>>(W2, WT2, 512, 256, mode);
    transpose_kernel<<<(512 * 128 + 255) / 256, 256, 0, stream>>>(W3, WT3, 512, 128, mode);
    cvt_kernel<<<1, 256, 0, stream>>>(b1, bb1, 256, mode);
    cvt_kernel<<<1, 256, 0, stream>>>(b2, bb2, 256, mode);
    cvt_kernel<<<1, 256, 0, stream>>>(b3, bb3, 128, mode);
    pack_kernel<<<(NN * 16 + 255) / 256, 256, 0, stream>>>(x, buf, mode);

    const int SPMM_GRID = NN / 4;          // 4 waves (nodes) per 256-thread block
    const int GB = (NN + 127) / 128;       // 391 gemm row-blocks

    // L1: buf = [x(0:128) | x1(128:256)]; gemm K=256 in-place -> cols 0:256
    spmm_kernel<2><<<SPMM_GRID, 256, 0, stream>>>(buf, 512, rp2, csr, dinv, buf + 128, 512);
    gemm_lds_kernel<8, 4><<<GB, 512, 0, stream>>>(buf, 512, WT1, bb1, buf, 512, NN, 1, 0, mode);
    // L2..L4: x1 into cols 256:512, gemm K=512 in-place -> cols 0:256
    spmm_kernel<4><<<SPMM_GRID, 256, 0, stream>>>(buf, 512, rp2, csr, dinv, buf + 256, 512);
    gemm_lds_kernel<16, 4><<<GB, 512, 0, stream>>>(buf, 512, WT2, bb2, buf, 512, NN, 1, 0, mode);
    spmm_kernel<4><<<SPMM_GRID, 256, 0, stream>>>(buf, 512, rp2, csr, dinv, buf + 256, 512);
    gemm_lds_kernel<16, 4><<<GB, 512, 0, stream>>>(buf, 512, WT2, bb2, buf, 512, NN, 1, 0, mode);
    spmm_kernel<4><<<SPMM_GRID, 256, 0, stream>>>(buf, 512, rp2, csr, dinv, buf + 256, 512);
    gemm_lds_kernel<16, 4><<<GB, 512, 0, stream>>>(buf, 512, WT2, bb2, buf, 512, NN, 1, 0, mode);
    // L5 (no tanh) -> d_out (50000 x 128, bf16 or fp32 per mode)
    spmm_kernel<4><<<SPMM_GRID, 256, 0, stream>>>(buf, 512, rp2, csr, dinv, buf + 256, 512);
    gemm_lds_kernel<16, 2><<<GB, 256, 0, stream>>>(buf, 512, WT3, bb3, d_out, 128, NN, 0, 1, mode);
}